// Round 8
// baseline (644.881 us; speedup 1.0000x reference)
//
#include <hip/hip_runtime.h>
#include <math.h>

#define HH 128
#define WW 128
#define HWSZ (128*128)

typedef __attribute__((ext_vector_type(8))) short short8;
typedef __attribute__((ext_vector_type(4))) float float4v;

__device__ inline short f2bf(float f) {
  unsigned x = __float_as_uint(f);
  unsigned r = (x + 0x7fffu + ((x >> 16) & 1u)) >> 16;
  return (short)r;
}
__device__ inline float bf2f(unsigned short u) {
  return __uint_as_float(((unsigned)u) << 16);
}
// XOR-swizzled short-index of 8-short granule g in LDS row `row` (row stride 32 shorts).
__device__ inline int swz(int row, int g) {
  return row * 32 + ((g ^ ((row >> 1) & 3)) << 3);
}

// ---------------- x: NCHW fp32 -> NHWC bf16 ----
__global__ __launch_bounds__(256) void xcvt_kernel(const float* __restrict__ x,
                                                   short* __restrict__ xbf) {
  __shared__ short tile[32 * 264];
  const int t = threadIdx.x;
  const int h = blockIdx.x, b = blockIdx.y;
  for (int wc = 0; wc < 4; wc++) {
    const int w0 = wc * 32;
    __syncthreads();
    #pragma unroll
    for (int coi = 0; coi < 8; coi++) {
      int ci = coi * 32 + (t >> 3);
      int wq = t & 7;
      float4v f = *(const float4v*)&x[((size_t)b * 256 + ci) * HWSZ + h * WW + w0 + wq * 4];
      tile[(wq * 4 + 0) * 264 + ci] = f2bf(f.x);
      tile[(wq * 4 + 1) * 264 + ci] = f2bf(f.y);
      tile[(wq * 4 + 2) * 264 + ci] = f2bf(f.z);
      tile[(wq * 4 + 3) * 264 + ci] = f2bf(f.w);
    }
    __syncthreads();
    #pragma unroll
    for (int pass = 0; pass < 4; pass++) {
      int wl = pass * 8 + (t >> 5);
      int ci8 = (t & 31) * 8;
      short8 v = *(const short8*)&tile[wl * 264 + ci8];
      *(short8*)&xbf[(((size_t)b * HH + h) * WW + w0 + wl) * 256 + ci8] = v;
    }
  }
}

// ---------------- weight converts (BN scale folded), MFMA-frag-friendly layout ----
// Storage: [ci_chunk][tap][co_half*128 + co_perm][ci_in32], co_perm = lr*8 + ni
// where co_local = ni*16 + lr  (lr in [0,16), ni in [0,8)).
// A lane (lr,lk) needs perm rows lr*8 + 0..7 at short-offset lk*8: 8 loads 64 B apart.
__device__ inline int co_perm_idx(int co /*0..255 global*/) {
  int half = co >> 7;
  int cl = co & 127;
  int ni = cl >> 4, lr = cl & 15;
  return half * 128 + lr * 8 + ni;
}

__global__ void wcvt3_kernel(const float* __restrict__ w, const float* __restrict__ g,
                             const float* __restrict__ v, short* __restrict__ out,
                             int Cin, int CoutW, int co_off) {
  int idx = blockIdx.x * blockDim.x + threadIdx.x;
  int total = CoutW * Cin * 9;
  if (idx >= total) return;
  int t  = idx % 9;
  int ci = (idx / 9) % Cin;
  int co = idx / (9 * Cin);
  float s = g[co] * rsqrtf(v[co] + 1e-5f);
  int gco = co_off + co;
  size_t o = (((size_t)(ci >> 5) * 9 + t) * 256 + co_perm_idx(gco)) * 32 + (ci & 31);
  out[o] = f2bf(w[idx] * s);
}

__global__ void wcvt1_kernel(const float* __restrict__ w, const float* __restrict__ g,
                             const float* __restrict__ v, short* __restrict__ out,
                             int Cin, int CoutW) {
  int idx = blockIdx.x * blockDim.x + threadIdx.x;
  if (idx >= CoutW * Cin) return;
  int ci = idx % Cin;
  int co = idx / Cin;
  float s = g[co] * rsqrtf(v[co] + 1e-5f);
  size_t o = ((size_t)(ci >> 5) * 256 + co_perm_idx(co)) * 32 + (ci & 31);
  out[o] = f2bf(w[idx] * s);
}

// ---------------- MFMA implicit-GEMM conv3x3 (+optional fused 1x1) ----------------
// Block: 256 thr = 4 waves. Tile: M=128 px (one image row) x N=256 co.
// A (activations) staged in LDS (all 3 dy rows per 32-ci chunk, XOR-swizzled).
// B (weights) loaded global->VGPR directly in frag layout (L2-resident; no LDS).
// Chunks: CIN_A/32 of 9 taps each, then NB 1x1-chunks of 1 tap over xB.
template<int CIN_A, int NB, int SHIFT_MODE, bool SPLIT_OUT, bool OUT_F32>
__global__ __launch_bounds__(256, 2) void conv_mfma(
    const short* __restrict__ srcA, const short* __restrict__ xB,
    const short* __restrict__ wbA, const short* __restrict__ wbB,
    const float* __restrict__ g0, const float* __restrict__ b0,
    const float* __restrict__ m0, const float* __restrict__ v0,
    const float* __restrict__ g1, const float* __restrict__ b1,
    const float* __restrict__ m1, const float* __restrict__ v1,
    void* __restrict__ out0, void* __restrict__ out1)
{
  __shared__ short A_s[3 * 130 * 32];   // 24,960 B

  const int tid  = threadIdx.x;
  const int wave = tid >> 6;
  const int lane = tid & 63;
  const int wm = wave & 1;          // px half (64)
  const int wn = wave >> 1;         // co half (128)
  const int lr = lane & 15;
  const int lk = lane >> 4;

  const int h  = blockIdx.x & 127;
  const int b  = blockIdx.x >> 7;

  constexpr int ncA = CIN_A / 32;

  float4v acc[4][8];
  #pragma unroll
  for (int i = 0; i < 4; i++)
    #pragma unroll
    for (int j = 0; j < 8; j++) acc[i][j] = (float4v)(0.0f);

  for (int ch = 0; ch < ncA + NB; ch++) {
    const bool isA = (ch < ncA);
    __syncthreads();
    if (isA) {
      const int ci0 = ch * 32;
      // stage rows h-1..h+1 (zero-fill OOB): 3*130*4 = 1560 granules
      for (int g = tid; g < 1560; g += 256) {
        int dy  = g / 520;
        int rem = g - dy * 520;
        int wp = rem >> 2, q = rem & 3;
        int gw = wp - 1;
        int gh = h + dy - 1;
        short8 val = (short8)(0);
        if ((unsigned)gh < (unsigned)HH && (unsigned)gw < (unsigned)WW)
          val = *(const short8*)(srcA + (((size_t)b * HH + gh) * WW + gw) * CIN_A + ci0 + q * 8);
        *(short8*)&A_s[swz(dy * 130 + wp, q)] = val;
      }
    } else {
      const int ci0 = (ch - ncA) * 32;
      for (int g = tid; g < 512; g += 256) {
        int wp = g >> 2, q = g & 3;
        short8 val = *(const short8*)(xB + (((size_t)b * HH + h) * WW + wp) * 256 + ci0 + q * 8);
        *(short8*)&A_s[swz(wp, q)] = val;
      }
    }
    __syncthreads();

    if (isA) {
      // B base for this ci-chunk: [ch][tap][256 perm][32]
      const short* bch = wbA + ((size_t)ch * 9) * 256 * 32 + (wn * 128 + lr * 8) * 32 + lk * 8;
      #pragma unroll
      for (int tap = 0; tap < 9; tap++) {
        const short* bp = bch + (size_t)tap * 256 * 32;
        short8 bfr[8];
        #pragma unroll
        for (int ni = 0; ni < 8; ni++)
          bfr[ni] = *(const short8*)(bp + ni * 32);   // consecutive perm rows, 64 B apart
        const int dy = tap / 3, dx = tap % 3;
        const int rowbase = dy * 130 + dx;
        short8 af[4];
        #pragma unroll
        for (int mi = 0; mi < 4; mi++)
          af[mi] = *(const short8*)&A_s[swz(rowbase + wm * 64 + mi * 16 + lr, lk)];
        #pragma unroll
        for (int ni = 0; ni < 8; ni++)
          #pragma unroll
          for (int mi = 0; mi < 4; mi++)
            acc[mi][ni] = __builtin_amdgcn_mfma_f32_16x16x32_bf16(af[mi], bfr[ni], acc[mi][ni], 0, 0, 0);
      }
    } else {
      const int cb = ch - ncA;
      const short* bp = wbB + ((size_t)cb * 256 + wn * 128 + lr * 8) * 32 + lk * 8;
      short8 bfr[8];
      #pragma unroll
      for (int ni = 0; ni < 8; ni++)
        bfr[ni] = *(const short8*)(bp + ni * 32);     // consecutive perm rows, 64 B apart
      short8 af[4];
      #pragma unroll
      for (int mi = 0; mi < 4; mi++)
        af[mi] = *(const short8*)&A_s[swz(wm * 64 + mi * 16 + lr, lk)];
      #pragma unroll
      for (int ni = 0; ni < 8; ni++)
        #pragma unroll
        for (int mi = 0; mi < 4; mi++)
          acc[mi][ni] = __builtin_amdgcn_mfma_f32_16x16x32_bf16(af[mi], bfr[ni], acc[mi][ni], 0, 0, 0);
    }
  }

  // ---------- epilogue: +shift (from raw BN params), relu, store ----------
  #pragma unroll
  for (int ni = 0; ni < 8; ni++) {
    int c = wn * 128 + ni * 16 + lr;          // co 0..255
    float sh;
    if (SHIFT_MODE == 0) {
      float s = g0[c] * rsqrtf(v0[c] + 1e-5f);
      sh = b0[c] - m0[c] * s;
    } else if (SHIFT_MODE == 1) {
      int cc = c & 127;
      const float* gg = (c < 128) ? g0 : g1;
      const float* bb = (c < 128) ? b0 : b1;
      const float* mm = (c < 128) ? m0 : m1;
      const float* vv = (c < 128) ? v0 : v1;
      float s = gg[cc] * rsqrtf(vv[cc] + 1e-5f);
      sh = bb[cc] - mm[cc] * s;
    } else {
      float s0 = g0[c] * rsqrtf(v0[c] + 1e-5f);
      float s1 = g1[c] * rsqrtf(v1[c] + 1e-5f);
      sh = (b0[c] - m0[c] * s0) + (b1[c] - m1[c] * s1);
    }
    #pragma unroll
    for (int mi = 0; mi < 4; mi++) {
      int px = wm * 64 + mi * 16 + lk * 4;
      float4v v = acc[mi][ni];
      v.x = fmaxf(v.x + sh, 0.0f);
      v.y = fmaxf(v.y + sh, 0.0f);
      v.z = fmaxf(v.z + sh, 0.0f);
      v.w = fmaxf(v.w + sh, 0.0f);
      if (OUT_F32) {
        float* ob = (float*)out0;
        *(float4v*)(ob + ((size_t)b * 256 + c) * HWSZ + (size_t)h * WW + px) = v;
      } else if (SPLIT_OUT) {
        short* ob = (short*)((c < 128) ? out0 : out1);
        size_t base = (((size_t)b * HH + h) * WW + px) * 128 + (c & 127);
        ob[base      ] = f2bf(v.x);
        ob[base + 128 ] = f2bf(v.y);
        ob[base + 256 ] = f2bf(v.z);
        ob[base + 384 ] = f2bf(v.w);
      } else {
        short* ob = (short*)out0;
        size_t base = (((size_t)b * HH + h) * WW + px) * 256 + c;
        ob[base      ] = f2bf(v.x);
        ob[base + 256 ] = f2bf(v.y);
        ob[base + 512 ] = f2bf(v.z);
        ob[base + 768 ] = f2bf(v.w);
      }
    }
  }
}

// ---------------- reverse cummax over H on bf16 NHWC [b][h][w][128], in place
// LDS-staged: block per (b, w-pair): load [128h][2w][128c]=64KB coalesced (parallel),
// serial scan in LDS (conflict-free), store back coalesced.
__global__ __launch_bounds__(256) void colscan_kernel(short* __restrict__ p) {
  __shared__ short pl[128 * 2 * 128];
  const int tid = threadIdx.x;
  const int w0 = blockIdx.x * 2;
  const int b  = blockIdx.y;
  #pragma unroll
  for (int i = 0; i < 16; i++) {
    int g = tid + i * 256;                 // g = hh*32 + wl*16 + c8
    int hh = g >> 5; int rem = g & 31; int wl = rem >> 4; int c8 = rem & 15;
    *(short8*)&pl[g * 8] =
      *(const short8*)(p + (((size_t)b * HH + hh) * WW + w0 + wl) * 128 + c8 * 8);
  }
  __syncthreads();
  {
    int wl = tid >> 7, c = tid & 127;
    float m = -INFINITY;
    for (int hh = HH - 1; hh >= 0; hh--) {
      int a = hh * 256 + wl * 128 + c;
      m = fmaxf(m, bf2f((unsigned short)pl[a]));
      pl[a] = (short)f2bf(m);
    }
  }
  __syncthreads();
  #pragma unroll
  for (int i = 0; i < 16; i++) {
    int g = tid + i * 256;
    int hh = g >> 5; int rem = g & 31; int wl = rem >> 4; int c8 = rem & 15;
    *(short8*)(p + (((size_t)b * HH + hh) * WW + w0 + wl) * 128 + c8 * 8) =
      *(const short8*)&pl[g * 8];
  }
}

// ---------------- reverse cummax over W on p2 + add p1 -> p1 (bf16 NHWC C=128)
__global__ __launch_bounds__(256) void rowscan_add_kernel(
    const short* __restrict__ p2, short* __restrict__ p1) {
  __shared__ short pl[128 * 128];
  const int tid = threadIdx.x;
  const int hb = blockIdx.x;
  const int b  = blockIdx.y;
  const size_t base = (((size_t)b * HH + hb) * WW) * 128;

  #pragma unroll
  for (int i = 0; i < 8; i++) {
    int idx = tid + i * 256;
    *(short8*)&pl[idx * 8] = *(const short8*)(p2 + base + (size_t)idx * 8);
  }
  __syncthreads();
  if (tid < 128) {
    float m = -INFINITY;
    for (int w = WW - 1; w >= 0; w--) {
      int a = w * 128 + tid;
      m = fmaxf(m, bf2f((unsigned short)pl[a]));
      pl[a] = (short)f2bf(m);
    }
  }
  __syncthreads();
  #pragma unroll
  for (int i = 0; i < 8; i++) {
    int idx = tid + i * 256;
    short8 sv = *(const short8*)&pl[idx * 8];
    short8 ov = *(const short8*)(p1 + base + (size_t)idx * 8);
    short8 rv;
    #pragma unroll
    for (int j = 0; j < 8; j++)
      rv[j] = f2bf(bf2f((unsigned short)sv[j]) + bf2f((unsigned short)ov[j]));
    *(short8*)(p1 + base + (size_t)idx * 8) = rv;
  }
}

extern "C" void kernel_launch(void* const* d_in, const int* in_sizes, int n_in,
                              void* d_out, int out_size, void* d_ws, size_t ws_size,
                              hipStream_t stream) {
  const float* x    = (const float*)d_in[0];
  const float* w_p1 = (const float*)d_in[1];
  const float* g_p1 = (const float*)d_in[2];
  const float* b_p1 = (const float*)d_in[3];
  const float* m_p1 = (const float*)d_in[4];
  const float* v_p1 = (const float*)d_in[5];
  const float* w_p2 = (const float*)d_in[6];
  const float* g_p2 = (const float*)d_in[7];
  const float* b_p2 = (const float*)d_in[8];
  const float* m_p2 = (const float*)d_in[9];
  const float* v_p2 = (const float*)d_in[10];
  const float* w_c1 = (const float*)d_in[11];
  const float* g_c1 = (const float*)d_in[12];
  const float* b_c1 = (const float*)d_in[13];
  const float* m_c1 = (const float*)d_in[14];
  const float* v_c1 = (const float*)d_in[15];
  const float* w_c2 = (const float*)d_in[16];
  const float* g_c2 = (const float*)d_in[17];
  const float* b_c2 = (const float*)d_in[18];
  const float* m_c2 = (const float*)d_in[19];
  const float* v_c2 = (const float*)d_in[20];
  const float* w_p3 = (const float*)d_in[21];
  const float* g_p3 = (const float*)d_in[22];
  const float* b_p3 = (const float*)d_in[23];
  const float* m_p3 = (const float*)d_in[24];
  const float* v_p3 = (const float*)d_in[25];

  char* ws = (char*)d_ws;
  // Persistent tensors — total exactly 100,663,296 B.
  short* p1  = (short*)(ws + 0);          // bf16 NHWC [4][128][128][128]  16 MB
  short* p2  = (short*)(ws + 16777216);   // bf16 NHWC [4][128][128][128]  16 MB
  short* r   = (short*)(ws + 33554432);   // bf16 NHWC [4][128][128][256]  32 MB
  short* xbf = (short*)(ws + 67108864);   // bf16 NHWC [4][128][128][256]  32 MB
  // Weight buffers overlay dead regions (stream-ordered):
  short* wb12 = r;                        // [8][9][256][32]; dead before c1 writes r
  short* wbc1 = p2;                       // [4][9][256][32]; written after rowscan_add
  short* wbc2 = (short*)(ws + 16777216 + 589824);  // [8][256][32], in p2 region
  short* wbp3 = p1;                       // [8][9][256][32]; written after c1

  // x -> NHWC bf16
  xcvt_kernel<<<dim3(128, 4), 256, 0, stream>>>(x, xbf);

  // weights for p1|p2 (into r region)
  wcvt3_kernel<<<(128 * 256 * 9 + 255) / 256, 256, 0, stream>>>(w_p1, g_p1, v_p1, wb12, 256, 128, 0);
  wcvt3_kernel<<<(128 * 256 * 9 + 255) / 256, 256, 0, stream>>>(w_p2, g_p2, v_p2, wb12, 256, 128, 128);

  // p1|p2 = relu(bn(conv3x3(x)))
  conv_mfma<256, 0, 1, true, false><<<dim3(512), 256, 0, stream>>>(
      xbf, nullptr, wb12, nullptr,
      g_p1, b_p1, m_p1, v_p1, g_p2, b_p2, m_p2, v_p2, (void*)p1, (void*)p2);

  // corner pooling: cp1 in-place on p1, then s = rowscan(p2) + cp1 -> p1
  colscan_kernel<<<dim3(64, 4), 256, 0, stream>>>(p1);
  rowscan_add_kernel<<<dim3(128, 4), 256, 0, stream>>>(p2, p1);

  // weights for c1 (3x3) and c2 (1x1) into p2 region (p2 dead now)
  wcvt3_kernel<<<(256 * 128 * 9 + 255) / 256, 256, 0, stream>>>(w_c1, g_c1, v_c1, wbc1, 128, 256, 0);
  wcvt1_kernel<<<(256 * 256 + 255) / 256, 256, 0, stream>>>(w_c2, g_c2, v_c2, wbc2, 256, 256);

  // r = relu(bn1(conv3x3(s)) + bn2(conv1x1(x)))
  conv_mfma<128, 8, 2, false, false><<<dim3(512), 256, 0, stream>>>(
      p1, xbf, wbc1, wbc2,
      g_c1, b_c1, m_c1, v_c1, g_c2, b_c2, m_c2, v_c2, (void*)r, nullptr);

  // weights for p3 into p1 region (p1 dead now)
  wcvt3_kernel<<<(256 * 256 * 9 + 255) / 256, 256, 0, stream>>>(w_p3, g_p3, v_p3, wbp3, 256, 256, 0);

  // out = relu(bn(conv3x3(r)))  — fp32 NCHW float4 stores
  conv_mfma<256, 0, 0, false, true><<<dim3(512), 256, 0, stream>>>(
      r, nullptr, wbp3, nullptr,
      g_p3, b_p3, m_p3, v_p3, nullptr, nullptr, nullptr, nullptr, d_out, nullptr);
}